// Round 3
// baseline (8264.163 us; speedup 1.0000x reference)
//
#include <hip/hip_runtime.h>
#include <cstdint>
#include <cstddef>

#define BATCH   8
#define NPTS    16384
#define CFEAT   64
#define NPOINT  2048
#define NSAMPLE 32
#define DIN     124
#define D1      128
#define D2      128
#define D3      256
#define LN_EPS  1e-5f

// ---------------------------------------------------------------------------
// Kernel 1: farthest point sampling. One block per batch, 1024 threads.
// Per-thread state: px/py as 32 NAMED SCALARS (macro-expanded; arrays were
// being demoted to scratch/global-reload at the 64-VGPR heuristic cap, giving
// 969 MB HBM fetch per dispatch). pz and the running min-dist live in LDS
// (2 x 64 KB). Exact reference f32 math: separate __fsub/__fmul/__fadd (no
// FMA contraction), fminf, argmax tie-break -> smallest index.
// ---------------------------------------------------------------------------
#define PTS16(F) F(0) F(1) F(2) F(3) F(4) F(5) F(6) F(7) \
                 F(8) F(9) F(10) F(11) F(12) F(13) F(14) F(15)

__global__ __launch_bounds__(1024, 4) void fps_kernel(
    const float* __restrict__ xyz, int* __restrict__ fps_idx,
    float* __restrict__ new_xyz)
{
  const int b = blockIdx.x;
  const int t = threadIdx.x;
  const float* X = xyz + (size_t)b * NPTS * 3;

  __shared__ float s_pz[16 * 1024];    // 64 KB
  __shared__ float s_dist[16 * 1024];  // 64 KB
  __shared__ float cbuf[3];
  __shared__ int   sfar;
  __shared__ float wvx[16], wvy[16], wvz[16], wvv[16];
  __shared__ int   wvi[16];

#define DECLP(i) float px##i, py##i;
  PTS16(DECLP)
#undef DECLP

#define LOADP(i) { int j = t + 1024 * i;            \
    px##i = X[3 * j + 0];                           \
    py##i = X[3 * j + 1];                           \
    s_pz[1024 * i + t]   = X[3 * j + 2];            \
    s_dist[1024 * i + t] = 1e10f; }
  PTS16(LOADP)
#undef LOADP

  if (t == 0) {
    cbuf[0] = X[0]; cbuf[1] = X[1]; cbuf[2] = X[2];
    sfar = 0;
  }
  __syncthreads();

  for (int s = 0; s < NPOINT; ++s) {
    const float cx = cbuf[0], cy = cbuf[1], cz = cbuf[2];
    const int   far = sfar;
    if (t == 0) {
      fps_idx[b * NPOINT + s] = far;
      float* o = new_xyz + ((size_t)b * NPOINT + s) * 3;
      o[0] = cx; o[1] = cy; o[2] = cz;
    }
    if (s == NPOINT - 1) break;

    float best = -1.0f, bx = 0.f, by = 0.f, bz = 0.f;
    int   bidx = 0;
#define STEP(i) {                                                        \
    float pz = s_pz[1024 * i + t];                                       \
    float dx = __fsub_rn(px##i, cx);                                     \
    float dy = __fsub_rn(py##i, cy);                                     \
    float dz = __fsub_rn(pz, cz);                                        \
    float d  = __fadd_rn(__fadd_rn(__fmul_rn(dx, dx), __fmul_rn(dy, dy)),\
                         __fmul_rn(dz, dz));                             \
    float nd = fminf(s_dist[1024 * i + t], d);                           \
    s_dist[1024 * i + t] = nd;                                           \
    if (nd > best) { best = nd; bidx = t + 1024 * i;                     \
                     bx = px##i; by = py##i; bz = pz; } }
    PTS16(STEP)
#undef STEP

    // wave reduction, carry coords of the winner
#pragma unroll
    for (int off = 32; off >= 1; off >>= 1) {
      float ov = __shfl_xor(best, off);
      int   oi = __shfl_xor(bidx, off);
      float ox = __shfl_xor(bx, off);
      float oy = __shfl_xor(by, off);
      float oz = __shfl_xor(bz, off);
      if (ov > best || (ov == best && oi < bidx)) {
        best = ov; bidx = oi; bx = ox; by = oy; bz = oz;
      }
    }
    if ((t & 63) == 0) {
      int w = t >> 6;
      wvv[w] = best; wvi[w] = bidx; wvx[w] = bx; wvy[w] = by; wvz[w] = bz;
    }
    __syncthreads();
    if (t < 16) {
      best = wvv[t]; bidx = wvi[t]; bx = wvx[t]; by = wvy[t]; bz = wvz[t];
#pragma unroll
      for (int off = 8; off >= 1; off >>= 1) {
        float ov = __shfl_xor(best, off);
        int   oi = __shfl_xor(bidx, off);
        float ox = __shfl_xor(bx, off);
        float oy = __shfl_xor(by, off);
        float oz = __shfl_xor(bz, off);
        if (ov > best || (ov == best && oi < bidx)) {
          best = ov; bidx = oi; bx = ox; by = oy; bz = oz;
        }
      }
      if (t == 0) { sfar = bidx; cbuf[0] = bx; cbuf[1] = by; cbuf[2] = bz; }
    }
    __syncthreads();
  }
}

// ---------------------------------------------------------------------------
// Kernel 2: exact 32-NN per centroid. One wave handles 16 centroids; the
// current top-32 (sorted ascending by (d2, idx)) lives one entry per lane in
// lanes 0..31. Candidates pass a threshold ballot and are inserted in
// ascending global-index order via a branch-free wave-wide shift. Same
// no-FMA f32 distance rounding as the reference.
// ---------------------------------------------------------------------------
__global__ __launch_bounds__(256, 4) void knn_kernel(
    const float* __restrict__ xyz, const float* __restrict__ new_xyz,
    int* __restrict__ knn_idx)
{
  const int lane = threadIdx.x & 63;
  const int wid  = threadIdx.x >> 6;
  const int gidbase = blockIdx.x * 64 + wid * 16;   // 16 centroids per wave
  const int b = gidbase / NPOINT;                   // uniform per block
  const float* X = xyz + (size_t)b * NPTS * 3;

  float cx[16], cy[16], cz[16];
#pragma unroll
  for (int c = 0; c < 16; ++c) {
    const float* p = new_xyz + (size_t)(gidbase + c) * 3;
    cx[c] = p[0]; cy[c] = p[1]; cz[c] = p[2];
  }

  float qd[16]; int qi[16]; float T[16];
#pragma unroll
  for (int c = 0; c < 16; ++c) { qd[c] = 3.4e38f; qi[c] = 0; T[c] = 3.4e38f; }

  for (int base = 0; base < NPTS; base += 64) {
    const int j = base + lane;
    const float x = X[3 * j + 0];
    const float y = X[3 * j + 1];
    const float z = X[3 * j + 2];
#pragma unroll
    for (int c = 0; c < 16; ++c) {
      float dx = __fsub_rn(x, cx[c]);
      float dy = __fsub_rn(y, cy[c]);
      float dz = __fsub_rn(z, cz[c]);
      float v  = __fadd_rn(__fadd_rn(__fmul_rn(dx, dx), __fmul_rn(dy, dy)),
                           __fmul_rn(dz, dz));
      unsigned long long m = __ballot(v < T[c]);
      while (m) {
        int bit = __ffsll(m) - 1;
        m &= m - 1;
        float vb = __shfl(v, bit);
        if (vb < T[c]) {                 // re-check: T shrinks as we insert
          int   jb = base + bit;
          float du = __shfl_up(qd[c], 1);
          int   iu = __shfl_up(qi[c], 1);
          bool c2 = (lane > 0) && (vb < du);
          bool c1 = vb < qd[c];
          qd[c] = c2 ? du : (c1 ? vb : qd[c]);
          qi[c] = c2 ? iu : (c1 ? jb : qi[c]);
          T[c] = __shfl(qd[c], 31);
        }
      }
    }
  }
#pragma unroll
  for (int c = 0; c < 16; ++c) {
    if (lane < 32) knn_idx[(size_t)(gidbase + c) * NSAMPLE + lane] = qi[c];
  }
}

// ---------------------------------------------------------------------------
// Kernel 3: gather + NeRF encoding + 3-layer MLP (f32) + max over k.
// One block (128 threads) per centroid. Activations kept transposed in LDS:
// bufT[i][r], stride 36 floats (16B-aligned rows, bank-spread). Thread t owns
// output column t; per GEMM step: 1 coalesced weight load + broadcast
// ds_read_b128 of a 32-row activation slice + 32 FMAs.
// ---------------------------------------------------------------------------
__global__ __launch_bounds__(128, 4) void mlp_kernel(
    const float* __restrict__ xyz, const float* __restrict__ features,
    const float* __restrict__ new_xyz, const int* __restrict__ knn_idx,
    const float* __restrict__ W1, const float* __restrict__ b1,
    const float* __restrict__ g1, const float* __restrict__ be1,
    const float* __restrict__ W2, const float* __restrict__ b2,
    const float* __restrict__ g2, const float* __restrict__ be2,
    const float* __restrict__ W3, const float* __restrict__ b3,
    float* __restrict__ out)
{
  const int g = blockIdx.x;          // centroid id, 0..B*NPOINT-1
  const int b = g / NPOINT;
  const int t = threadIdx.x;         // 0..127

  __shared__ float bufT[128 * 36];   // [i][r] transposed activations
  __shared__ int   ki[32];
  __shared__ float cen[3];
  __shared__ float red[32][4][2];
  __shared__ float lnp[32][2];

  if (t < 32) ki[t] = knn_idx[(size_t)g * NSAMPLE + t];
  if (t < 3)  cen[t] = new_xyz[(size_t)g * 3 + t];
  __syncthreads();

  // ---- gather features into bufT rows 0..63 ----
  {
    int r = t & 31, cs = (t >> 5) << 4;
    const float* frow = features + ((size_t)b * NPTS + ki[r]) * CFEAT + cs;
#pragma unroll
    for (int u = 0; u < 4; ++u) {
      float4 f = *(const float4*)(frow + 4 * u);
      bufT[(cs + 4 * u + 0) * 36 + r] = f.x;
      bufT[(cs + 4 * u + 1) * 36 + r] = f.y;
      bufT[(cs + 4 * u + 2) * 36 + r] = f.z;
      bufT[(cs + 4 * u + 3) * 36 + r] = f.w;
    }
  }
  // ---- positional encoding into bufT rows 64..123 ----
  if (t < 32) {
    const float* p = xyz + ((size_t)b * NPTS + ki[t]) * 3;
    float rx = p[0] - cen[0];
    float ry = p[1] - cen[1];
    float rz = p[2] - cen[2];
#pragma unroll
    for (int l = 0; l < 10; ++l) {
      float sc = (float)(1 << l);
      float ax = rx * sc, ay = ry * sc, az = rz * sc;
      int base = (64 + l * 6) * 36 + t;
      bufT[base + 0 * 36] = __sinf(ax);
      bufT[base + 1 * 36] = __sinf(ay);
      bufT[base + 2 * 36] = __sinf(az);
      bufT[base + 3 * 36] = __cosf(ax);
      bufT[base + 4 * 36] = __cosf(ay);
      bufT[base + 5 * 36] = __cosf(az);
    }
  }
  __syncthreads();

  float acc[32];

  // ================= layer 1 =================
  {
    float bias = b1[t];
#pragma unroll
    for (int r = 0; r < 32; ++r) acc[r] = bias;
    for (int i = 0; i < DIN; ++i) {
      float w = W1[i * D1 + t];
      const float* hr = &bufT[i * 36];
#pragma unroll
      for (int r = 0; r < 32; ++r) acc[r] = fmaf(hr[r], w, acc[r]);
    }
  }
  // LN1 + relu -> bufT[t][r]
  {
    __syncthreads();
#pragma unroll
    for (int r = 0; r < 32; ++r) bufT[t * 36 + r] = acc[r];
    __syncthreads();
    {
      int r = t & 31, seg = t >> 5;
      float s = 0.f, ss = 0.f;
#pragma unroll
      for (int u = 0; u < 32; ++u) {
        float v = bufT[(seg * 32 + u) * 36 + r];
        s += v; ss = fmaf(v, v, ss);
      }
      red[r][seg][0] = s; red[r][seg][1] = ss;
    }
    __syncthreads();
    if (t < 32) {
      float s  = red[t][0][0] + red[t][1][0] + red[t][2][0] + red[t][3][0];
      float ss = red[t][0][1] + red[t][1][1] + red[t][2][1] + red[t][3][1];
      float m  = s * (1.0f / D1);
      float var = ss * (1.0f / D1) - m * m;
      lnp[t][0] = m;
      lnp[t][1] = rsqrtf(var + LN_EPS);
    }
    __syncthreads();
    float gg = g1[t], bb = be1[t];
#pragma unroll
    for (int r = 0; r < 32; ++r) {
      float v = (acc[r] - lnp[r][0]) * lnp[r][1];
      v = fmaf(v, gg, bb);
      bufT[t * 36 + r] = fmaxf(v, 0.f);
    }
    __syncthreads();
  }

  // ================= layer 2 =================
  {
    float bias = b2[t];
#pragma unroll
    for (int r = 0; r < 32; ++r) acc[r] = bias;
    for (int i = 0; i < D1; ++i) {
      float w = W2[i * D2 + t];
      const float* hr = &bufT[i * 36];
#pragma unroll
      for (int r = 0; r < 32; ++r) acc[r] = fmaf(hr[r], w, acc[r]);
    }
  }
  // LN2 + relu -> bufT[t][r]
  {
    __syncthreads();
#pragma unroll
    for (int r = 0; r < 32; ++r) bufT[t * 36 + r] = acc[r];
    __syncthreads();
    {
      int r = t & 31, seg = t >> 5;
      float s = 0.f, ss = 0.f;
#pragma unroll
      for (int u = 0; u < 32; ++u) {
        float v = bufT[(seg * 32 + u) * 36 + r];
        s += v; ss = fmaf(v, v, ss);
      }
      red[r][seg][0] = s; red[r][seg][1] = ss;
    }
    __syncthreads();
    if (t < 32) {
      float s  = red[t][0][0] + red[t][1][0] + red[t][2][0] + red[t][3][0];
      float ss = red[t][0][1] + red[t][1][1] + red[t][2][1] + red[t][3][1];
      float m  = s * (1.0f / D2);
      float var = ss * (1.0f / D2) - m * m;
      lnp[t][0] = m;
      lnp[t][1] = rsqrtf(var + LN_EPS);
    }
    __syncthreads();
    float gg = g2[t], bb = be2[t];
#pragma unroll
    for (int r = 0; r < 32; ++r) {
      float v = (acc[r] - lnp[r][0]) * lnp[r][1];
      v = fmaf(v, gg, bb);
      bufT[t * 36 + r] = fmaxf(v, 0.f);
    }
    __syncthreads();
  }

  // ================= layer 3 + max over k =================
  {
    float a0[32], a1[32];
    float bias0 = b3[t], bias1 = b3[t + 128];
#pragma unroll
    for (int r = 0; r < 32; ++r) { a0[r] = bias0; a1[r] = bias1; }
    for (int i = 0; i < D2; ++i) {
      float w0 = W3[i * D3 + t];
      float w1 = W3[i * D3 + t + 128];
      const float* hr = &bufT[i * 36];
#pragma unroll
      for (int r = 0; r < 32; ++r) {
        a0[r] = fmaf(hr[r], w0, a0[r]);
        a1[r] = fmaf(hr[r], w1, a1[r]);
      }
    }
    float m0 = a0[0], m1 = a1[0];
#pragma unroll
    for (int r = 1; r < 32; ++r) { m0 = fmaxf(m0, a0[r]); m1 = fmaxf(m1, a1[r]); }
    float* of = out + (size_t)g * D3;
    of[t] = m0;
    of[t + 128] = m1;
  }
}

// ---------------------------------------------------------------------------
extern "C" void kernel_launch(void* const* d_in, const int* in_sizes, int n_in,
                              void* d_out, int out_size, void* d_ws, size_t ws_size,
                              hipStream_t stream) {
  const float* xyz      = (const float*)d_in[0];
  const float* features = (const float*)d_in[1];
  const float* W1  = (const float*)d_in[2];
  const float* b1  = (const float*)d_in[3];
  const float* g1  = (const float*)d_in[4];
  const float* be1 = (const float*)d_in[5];
  const float* W2  = (const float*)d_in[6];
  const float* b2  = (const float*)d_in[7];
  const float* g2  = (const float*)d_in[8];
  const float* be2 = (const float*)d_in[9];
  const float* W3  = (const float*)d_in[10];
  const float* b3  = (const float*)d_in[11];
  // npoint / nsample are fixed by the problem (2048 / 32); dims hardcoded.

  float* new_xyz  = (float*)d_out;                                  // (B,NPOINT,3)
  float* new_feat = (float*)d_out + (size_t)BATCH * NPOINT * 3;     // (B,NPOINT,256)

  int* fps_idx = (int*)d_ws;                       // B*NPOINT ints   (64 KB)
  int* knn_idx = fps_idx + BATCH * NPOINT;         // B*NPOINT*32 ints (2 MB)

  fps_kernel<<<dim3(BATCH), dim3(1024), 0, stream>>>(xyz, fps_idx, new_xyz);
  knn_kernel<<<dim3((BATCH * NPOINT) / 64), dim3(256), 0, stream>>>(xyz, new_xyz, knn_idx);
  mlp_kernel<<<dim3(BATCH * NPOINT), dim3(128), 0, stream>>>(
      xyz, features, new_xyz, knn_idx,
      W1, b1, g1, be1, W2, b2, g2, be2, W3, b3, new_feat);
}

// Round 4
// 6839.281 us; speedup vs baseline: 1.2083x; 1.2083x over previous
//
#include <hip/hip_runtime.h>
#include <cstdint>
#include <cstddef>

#define BATCH   8
#define NPTS    16384
#define CFEAT   64
#define NPOINT  2048
#define NSAMPLE 32
#define DIN     124
#define D1      128
#define D2      128
#define D3      256
#define LN_EPS  1e-5f

// ---------------------------------------------------------------------------
// Kernel 1: farthest point sampling. One block per batch, 1024 threads,
// 16 points/thread. The allocator pins this kernel at 64 VGPRs regardless of
// __launch_bounds__ (rounds 1-3: 32+ floats of per-thread state -> 250+ MB/
// dispatch of spill traffic). So keep per-thread state UNDER the budget:
//   - x,y coords in LDS (2 x 64 KB, stride-1 conflict-free reads)
//   - z + running min-dist as 32 named scalars (~50 live VGPRs total)
//   - argmax tracks (value, code) only; winner coords re-read from global
//     by thread 0 once per step (L2-resident, bit-identical values).
// Exact reference f32 math: separate __fsub/__fmul/__fadd (no FMA
// contraction), fminf, argmax tie-break -> smallest index.
// ---------------------------------------------------------------------------
#define PTS16(F) F(0) F(1) F(2) F(3) F(4) F(5) F(6) F(7) \
                 F(8) F(9) F(10) F(11) F(12) F(13) F(14) F(15)

__global__ __launch_bounds__(1024) void fps_kernel(
    const float* __restrict__ xyz, int* __restrict__ fps_idx,
    float* __restrict__ new_xyz)
{
  const int b = blockIdx.x;
  const int t = threadIdx.x;
  const float* X = xyz + (size_t)b * NPTS * 3;

  __shared__ float s_px[16 * 1024];    // 64 KB
  __shared__ float s_py[16 * 1024];    // 64 KB
  __shared__ float cbuf[3];
  __shared__ int   sfar;
  __shared__ float wvv[16];
  __shared__ int   wvi[16];

#define DECLP(i) float pz##i, dd##i;
  PTS16(DECLP)
#undef DECLP

#define LOADP(i) { int j = t + 1024 * i;            \
    s_px[1024 * i + t] = X[3 * j + 0];              \
    s_py[1024 * i + t] = X[3 * j + 1];              \
    pz##i = X[3 * j + 2];                           \
    dd##i = 1e10f; }
  PTS16(LOADP)
#undef LOADP

  if (t == 0) {
    cbuf[0] = X[0]; cbuf[1] = X[1]; cbuf[2] = X[2];
    sfar = 0;
  }
  __syncthreads();

  for (int s = 0; s < NPOINT; ++s) {
    const float cx = cbuf[0], cy = cbuf[1], cz = cbuf[2];
    const int   far = sfar;
    if (t == 0) {
      fps_idx[b * NPOINT + s] = far;
      float* o = new_xyz + ((size_t)b * NPOINT + s) * 3;
      o[0] = cx; o[1] = cy; o[2] = cz;
    }
    if (s == NPOINT - 1) break;

    // keep the z coords pinned in VGPRs (blocks remat-from-global)
    asm volatile("" : "+v"(pz0), "+v"(pz1), "+v"(pz2), "+v"(pz3),
                      "+v"(pz4), "+v"(pz5), "+v"(pz6), "+v"(pz7),
                      "+v"(pz8), "+v"(pz9), "+v"(pz10), "+v"(pz11),
                      "+v"(pz12), "+v"(pz13), "+v"(pz14), "+v"(pz15));

    float best = -1.0f;
    int   code = 0;
#define STEP(i) {                                                        \
    float dx = __fsub_rn(s_px[1024 * i + t], cx);                        \
    float dy = __fsub_rn(s_py[1024 * i + t], cy);                        \
    float dz = __fsub_rn(pz##i, cz);                                     \
    float d  = __fadd_rn(__fadd_rn(__fmul_rn(dx, dx), __fmul_rn(dy, dy)),\
                         __fmul_rn(dz, dz));                             \
    float nd = fminf(dd##i, d);                                          \
    dd##i = nd;                                                          \
    if (nd > best) { best = nd; code = i; } }
    PTS16(STEP)
#undef STEP

    int bidx = t + (code << 10);
    // wave reduction on (value desc, index asc)
#pragma unroll
    for (int off = 32; off >= 1; off >>= 1) {
      float ov = __shfl_xor(best, off);
      int   oi = __shfl_xor(bidx, off);
      if (ov > best || (ov == best && oi < bidx)) { best = ov; bidx = oi; }
    }
    if ((t & 63) == 0) {
      int w = t >> 6;
      wvv[w] = best; wvi[w] = bidx;
    }
    __syncthreads();
    if (t < 16) {
      best = wvv[t]; bidx = wvi[t];
#pragma unroll
      for (int off = 8; off >= 1; off >>= 1) {
        float ov = __shfl_xor(best, off);
        int   oi = __shfl_xor(bidx, off);
        if (ov > best || (ov == best && oi < bidx)) { best = ov; bidx = oi; }
      }
      if (t == 0) {
        sfar = bidx;
        const float* w = X + 3 * (size_t)bidx;   // L2-resident; same bits
        cbuf[0] = w[0]; cbuf[1] = w[1]; cbuf[2] = w[2];
      }
    }
    __syncthreads();
  }
}

// ---------------------------------------------------------------------------
// Kernel 2: exact 32-NN per centroid. One wave handles 16 centroids; the
// current top-32 (sorted ascending by (d2, idx)) lives one entry per lane in
// lanes 0..31. Candidates pass a threshold ballot and are inserted in
// ascending global-index order via a branch-free wave-wide shift. Same
// no-FMA f32 distance rounding as the reference.
// ---------------------------------------------------------------------------
__global__ __launch_bounds__(256, 4) void knn_kernel(
    const float* __restrict__ xyz, const float* __restrict__ new_xyz,
    int* __restrict__ knn_idx)
{
  const int lane = threadIdx.x & 63;
  const int wid  = threadIdx.x >> 6;
  const int gidbase = blockIdx.x * 64 + wid * 16;   // 16 centroids per wave
  const int b = gidbase / NPOINT;                   // uniform per block
  const float* X = xyz + (size_t)b * NPTS * 3;

  float cx[16], cy[16], cz[16];
#pragma unroll
  for (int c = 0; c < 16; ++c) {
    const float* p = new_xyz + (size_t)(gidbase + c) * 3;
    cx[c] = p[0]; cy[c] = p[1]; cz[c] = p[2];
  }

  float qd[16]; int qi[16]; float T[16];
#pragma unroll
  for (int c = 0; c < 16; ++c) { qd[c] = 3.4e38f; qi[c] = 0; T[c] = 3.4e38f; }

  for (int base = 0; base < NPTS; base += 64) {
    const int j = base + lane;
    const float x = X[3 * j + 0];
    const float y = X[3 * j + 1];
    const float z = X[3 * j + 2];
#pragma unroll
    for (int c = 0; c < 16; ++c) {
      float dx = __fsub_rn(x, cx[c]);
      float dy = __fsub_rn(y, cy[c]);
      float dz = __fsub_rn(z, cz[c]);
      float v  = __fadd_rn(__fadd_rn(__fmul_rn(dx, dx), __fmul_rn(dy, dy)),
                           __fmul_rn(dz, dz));
      unsigned long long m = __ballot(v < T[c]);
      while (m) {
        int bit = __ffsll(m) - 1;
        m &= m - 1;
        float vb = __shfl(v, bit);
        if (vb < T[c]) {                 // re-check: T shrinks as we insert
          int   jb = base + bit;
          float du = __shfl_up(qd[c], 1);
          int   iu = __shfl_up(qi[c], 1);
          bool c2 = (lane > 0) && (vb < du);
          bool c1 = vb < qd[c];
          qd[c] = c2 ? du : (c1 ? vb : qd[c]);
          qi[c] = c2 ? iu : (c1 ? jb : qi[c]);
          T[c] = __shfl(qd[c], 31);
        }
      }
    }
  }
#pragma unroll
  for (int c = 0; c < 16; ++c) {
    if (lane < 32) knn_idx[(size_t)(gidbase + c) * NSAMPLE + lane] = qi[c];
  }
}

// ---------------------------------------------------------------------------
// Kernel 3: gather + NeRF encoding + 3-layer MLP (f32) + max over k.
// One block (128 threads) per centroid. Activations kept transposed in LDS:
// bufT[i][r], stride 36 floats (16B-aligned rows, bank-spread). Thread t owns
// output column t; per GEMM step: 1 coalesced weight load + broadcast
// ds_read_b128 of a 32-row activation slice + 32 FMAs.
// ---------------------------------------------------------------------------
__global__ __launch_bounds__(128, 4) void mlp_kernel(
    const float* __restrict__ xyz, const float* __restrict__ features,
    const float* __restrict__ new_xyz, const int* __restrict__ knn_idx,
    const float* __restrict__ W1, const float* __restrict__ b1,
    const float* __restrict__ g1, const float* __restrict__ be1,
    const float* __restrict__ W2, const float* __restrict__ b2,
    const float* __restrict__ g2, const float* __restrict__ be2,
    const float* __restrict__ W3, const float* __restrict__ b3,
    float* __restrict__ out)
{
  const int g = blockIdx.x;          // centroid id, 0..B*NPOINT-1
  const int b = g / NPOINT;
  const int t = threadIdx.x;         // 0..127

  __shared__ float bufT[128 * 36];   // [i][r] transposed activations
  __shared__ int   ki[32];
  __shared__ float cen[3];
  __shared__ float red[32][4][2];
  __shared__ float lnp[32][2];

  if (t < 32) ki[t] = knn_idx[(size_t)g * NSAMPLE + t];
  if (t < 3)  cen[t] = new_xyz[(size_t)g * 3 + t];
  __syncthreads();

  // ---- gather features into bufT rows 0..63 ----
  {
    int r = t & 31, cs = (t >> 5) << 4;
    const float* frow = features + ((size_t)b * NPTS + ki[r]) * CFEAT + cs;
#pragma unroll
    for (int u = 0; u < 4; ++u) {
      float4 f = *(const float4*)(frow + 4 * u);
      bufT[(cs + 4 * u + 0) * 36 + r] = f.x;
      bufT[(cs + 4 * u + 1) * 36 + r] = f.y;
      bufT[(cs + 4 * u + 2) * 36 + r] = f.z;
      bufT[(cs + 4 * u + 3) * 36 + r] = f.w;
    }
  }
  // ---- positional encoding into bufT rows 64..123 ----
  if (t < 32) {
    const float* p = xyz + ((size_t)b * NPTS + ki[t]) * 3;
    float rx = p[0] - cen[0];
    float ry = p[1] - cen[1];
    float rz = p[2] - cen[2];
#pragma unroll
    for (int l = 0; l < 10; ++l) {
      float sc = (float)(1 << l);
      float ax = rx * sc, ay = ry * sc, az = rz * sc;
      int base = (64 + l * 6) * 36 + t;
      bufT[base + 0 * 36] = __sinf(ax);
      bufT[base + 1 * 36] = __sinf(ay);
      bufT[base + 2 * 36] = __sinf(az);
      bufT[base + 3 * 36] = __cosf(ax);
      bufT[base + 4 * 36] = __cosf(ay);
      bufT[base + 5 * 36] = __cosf(az);
    }
  }
  __syncthreads();

  float acc[32];

  // ================= layer 1 =================
  {
    float bias = b1[t];
#pragma unroll
    for (int r = 0; r < 32; ++r) acc[r] = bias;
    for (int i = 0; i < DIN; ++i) {
      float w = W1[i * D1 + t];
      const float* hr = &bufT[i * 36];
#pragma unroll
      for (int r = 0; r < 32; ++r) acc[r] = fmaf(hr[r], w, acc[r]);
    }
  }
  // LN1 + relu -> bufT[t][r]
  {
    __syncthreads();
#pragma unroll
    for (int r = 0; r < 32; ++r) bufT[t * 36 + r] = acc[r];
    __syncthreads();
    {
      int r = t & 31, seg = t >> 5;
      float s = 0.f, ss = 0.f;
#pragma unroll
      for (int u = 0; u < 32; ++u) {
        float v = bufT[(seg * 32 + u) * 36 + r];
        s += v; ss = fmaf(v, v, ss);
      }
      red[r][seg][0] = s; red[r][seg][1] = ss;
    }
    __syncthreads();
    if (t < 32) {
      float s  = red[t][0][0] + red[t][1][0] + red[t][2][0] + red[t][3][0];
      float ss = red[t][0][1] + red[t][1][1] + red[t][2][1] + red[t][3][1];
      float m  = s * (1.0f / D1);
      float var = ss * (1.0f / D1) - m * m;
      lnp[t][0] = m;
      lnp[t][1] = rsqrtf(var + LN_EPS);
    }
    __syncthreads();
    float gg = g1[t], bb = be1[t];
#pragma unroll
    for (int r = 0; r < 32; ++r) {
      float v = (acc[r] - lnp[r][0]) * lnp[r][1];
      v = fmaf(v, gg, bb);
      bufT[t * 36 + r] = fmaxf(v, 0.f);
    }
    __syncthreads();
  }

  // ================= layer 2 =================
  {
    float bias = b2[t];
#pragma unroll
    for (int r = 0; r < 32; ++r) acc[r] = bias;
    for (int i = 0; i < D1; ++i) {
      float w = W2[i * D2 + t];
      const float* hr = &bufT[i * 36];
#pragma unroll
      for (int r = 0; r < 32; ++r) acc[r] = fmaf(hr[r], w, acc[r]);
    }
  }
  // LN2 + relu -> bufT[t][r]
  {
    __syncthreads();
#pragma unroll
    for (int r = 0; r < 32; ++r) bufT[t * 36 + r] = acc[r];
    __syncthreads();
    {
      int r = t & 31, seg = t >> 5;
      float s = 0.f, ss = 0.f;
#pragma unroll
      for (int u = 0; u < 32; ++u) {
        float v = bufT[(seg * 32 + u) * 36 + r];
        s += v; ss = fmaf(v, v, ss);
      }
      red[r][seg][0] = s; red[r][seg][1] = ss;
    }
    __syncthreads();
    if (t < 32) {
      float s  = red[t][0][0] + red[t][1][0] + red[t][2][0] + red[t][3][0];
      float ss = red[t][0][1] + red[t][1][1] + red[t][2][1] + red[t][3][1];
      float m  = s * (1.0f / D2);
      float var = ss * (1.0f / D2) - m * m;
      lnp[t][0] = m;
      lnp[t][1] = rsqrtf(var + LN_EPS);
    }
    __syncthreads();
    float gg = g2[t], bb = be2[t];
#pragma unroll
    for (int r = 0; r < 32; ++r) {
      float v = (acc[r] - lnp[r][0]) * lnp[r][1];
      v = fmaf(v, gg, bb);
      bufT[t * 36 + r] = fmaxf(v, 0.f);
    }
    __syncthreads();
  }

  // ================= layer 3 + max over k =================
  {
    float a0[32], a1[32];
    float bias0 = b3[t], bias1 = b3[t + 128];
#pragma unroll
    for (int r = 0; r < 32; ++r) { a0[r] = bias0; a1[r] = bias1; }
    for (int i = 0; i < D2; ++i) {
      float w0 = W3[i * D3 + t];
      float w1 = W3[i * D3 + t + 128];
      const float* hr = &bufT[i * 36];
#pragma unroll
      for (int r = 0; r < 32; ++r) {
        a0[r] = fmaf(hr[r], w0, a0[r]);
        a1[r] = fmaf(hr[r], w1, a1[r]);
      }
    }
    float m0 = a0[0], m1 = a1[0];
#pragma unroll
    for (int r = 1; r < 32; ++r) { m0 = fmaxf(m0, a0[r]); m1 = fmaxf(m1, a1[r]); }
    float* of = out + (size_t)g * D3;
    of[t] = m0;
    of[t + 128] = m1;
  }
}

// ---------------------------------------------------------------------------
extern "C" void kernel_launch(void* const* d_in, const int* in_sizes, int n_in,
                              void* d_out, int out_size, void* d_ws, size_t ws_size,
                              hipStream_t stream) {
  const float* xyz      = (const float*)d_in[0];
  const float* features = (const float*)d_in[1];
  const float* W1  = (const float*)d_in[2];
  const float* b1  = (const float*)d_in[3];
  const float* g1  = (const float*)d_in[4];
  const float* be1 = (const float*)d_in[5];
  const float* W2  = (const float*)d_in[6];
  const float* b2  = (const float*)d_in[7];
  const float* g2  = (const float*)d_in[8];
  const float* be2 = (const float*)d_in[9];
  const float* W3  = (const float*)d_in[10];
  const float* b3  = (const float*)d_in[11];
  // npoint / nsample are fixed by the problem (2048 / 32); dims hardcoded.

  float* new_xyz  = (float*)d_out;                                  // (B,NPOINT,3)
  float* new_feat = (float*)d_out + (size_t)BATCH * NPOINT * 3;     // (B,NPOINT,256)

  int* fps_idx = (int*)d_ws;                       // B*NPOINT ints   (64 KB)
  int* knn_idx = fps_idx + BATCH * NPOINT;         // B*NPOINT*32 ints (2 MB)

  fps_kernel<<<dim3(BATCH), dim3(1024), 0, stream>>>(xyz, fps_idx, new_xyz);
  knn_kernel<<<dim3((BATCH * NPOINT) / 64), dim3(256), 0, stream>>>(xyz, new_xyz, knn_idx);
  mlp_kernel<<<dim3(BATCH * NPOINT), dim3(128), 0, stream>>>(
      xyz, features, new_xyz, knn_idx,
      W1, b1, g1, be1, W2, b2, g2, be2, W3, b3, new_feat);
}